// Round 15
// baseline (432.158 us; speedup 1.0000x reference)
//
#include <hip/hip_runtime.h>
#include <cstdint>

// CrossViewBlockTransformer on MI355X (gfx950), round 15.
// ZERO-BARRIER variant: every wave is fully independent (own block per
// iteration, own LDS regions, own vmcnt ledger). No s_barrier in the loop.
//   - Xq: 4x global_load_lds(16B) per wave into private [c][n] buffer
//     (per-lane source = (channel, row-quarter) of the wave's own block).
//   - Xr: 16x global_load_lds(width=4) per-lane gather into private buffer
//     -> Xr is 1-iteration-ahead WITHOUT +16 VGPRs (R13's spill trap).
//   - One counted s_waitcnt vmcnt(4) gate per iteration (drains Xr(t)+Xq(t),
//     leaves the 4 stores in flight). Waves slide freely past each other.
// Tests the last live hypothesis for the ~109us wall: 4-wave barrier convoy.
// Arithmetic identical to R4..R14 (absmax 0.1484375).

typedef float  f4    __attribute__((ext_vector_type(4)));
typedef float  f32x4 __attribute__((ext_vector_type(4)));
typedef short  s16x4 __attribute__((ext_vector_type(4)));
typedef short  s16x8 __attribute__((ext_vector_type(8)));
typedef unsigned short u16;
typedef __bf16 bf16;

#define MFMA16(a,b,c) __builtin_amdgcn_mfma_f32_16x16x16bf16_1k((a),(b),(c),0,0,0)
#define MFMA32(a,b,c) __builtin_amdgcn_mfma_f32_16x16x32_bf16((a),(b),(c),0,0,0)

// DPP row_ror:N over 16-lane rows
#define DPP_ROR(x, N)                                                         \
  __builtin_bit_cast(float, __builtin_amdgcn_mov_dpp(                         \
      __builtin_bit_cast(int, (x)), 0x120 + (N), 0xF, 0xF, 1))

// slot0=Wq(K32) slot1=Wk(K32) slot2=Wv(K32) slot3=Wfc(K16); 4 x 8KB
__device__ __align__(16) u16 g_wpack[4 * 4096];

__device__ __forceinline__ u16 bfbits(float x) {
  return __builtin_bit_cast(u16, (bf16)x);
}

__device__ __forceinline__ void gload_lds16(const float* g, float* l) {
  __builtin_amdgcn_global_load_lds(
      (const __attribute__((address_space(1))) void*)g,
      (__attribute__((address_space(3))) void*)l, 16, 0, 0);
}
__device__ __forceinline__ void gload_lds4(const float* g, float* l) {
  __builtin_amdgcn_global_load_lds(
      (const __attribute__((address_space(1))) void*)g,
      (__attribute__((address_space(3))) void*)l, 4, 0, 0);
}

// K32 frag: pack[t=a*2+b][l][j0..7] = W[16a + (l&15)][32b + 8*(l>>4) + j]
// K16 frag: pack[t=a*4+b][l][j0..3] = W[16a + (l&15)][16b + 4*(l>>4) + j]
__global__ void prep_w(const float* __restrict__ Wq, const float* __restrict__ Wk,
                       const float* __restrict__ Wv, const float* __restrict__ Wfc)
{
  const int t = threadIdx.x;  // 256 threads
  const float* Wm[3] = {Wq, Wk, Wv};
#pragma unroll
  for (int s = 0; s < 3; ++s) {
    const float* W = Wm[s];
    for (int e = t; e < 512; e += 256) {
      const int tile = e >> 6, l = e & 63;
      const int row = 16 * (tile >> 1) + (l & 15);
      const int col = 32 * (tile & 1) + 8 * (l >> 4);
#pragma unroll
      for (int j = 0; j < 8; ++j)
        g_wpack[s * 4096 + e * 8 + j] = bfbits(W[row * 64 + col + j]);
    }
  }
  for (int e = t; e < 1024; e += 256) {
    const int tile = e >> 6, l = e & 63;
    const int row = 16 * (tile >> 2) + (l & 15);
    const int col = 16 * (tile & 3) + 4 * (l >> 4);
#pragma unroll
    for (int j = 0; j < 4; ++j)
      g_wpack[3 * 4096 + e * 4 + j] = bfbits(Wfc[row * 64 + col + j]);
  }
}

__global__ void __launch_bounds__(256, 2)
cvbt15(const float* __restrict__ qx, const float* __restrict__ rx,
       const float* __restrict__ gw, const float* __restrict__ gb,
       float* __restrict__ out)
{
  // per-wave private regions; Xq layout: float idx = (c>>4)*264 + (c&15)*16 + n
  __shared__ __align__(16) float sQ[2][4][1056];   // ping-pong Xq/out (33.8KB)
  __shared__ __align__(16) float sXr[4][1024];     // Xr gather [m=kt*8+j][lane] (16KB)
  __shared__ u16   sP[4 * 320];                    // per-wave attn (2.5KB)
  __shared__ float sGn[128];                       // gamma|beta (0.5KB)

  const int tid  = threadIdx.x;
  const int wv   = tid >> 6, lane = tid & 63;
  const int n = lane & 15, g = lane >> 4, rp = n >> 2, wl = n & 3;

  if (tid < 128) sGn[tid] = (tid < 64) ? gw[tid] : gb[tid - 64];
  __syncthreads();  // ONLY barrier in the kernel (sGn visibility)

  // ---- persistent weight fragments (register-resident) ----
  s16x8 Wq8[4][2], Wk8[4][2], Wv8[4][2];
  s16x4 Wf4[4][4];
#pragma unroll
  for (int a = 0; a < 4; ++a) {
#pragma unroll
    for (int c2 = 0; c2 < 2; ++c2) {
      Wq8[a][c2] = *(const s16x8*)(g_wpack + 0 * 4096 + ((a * 2 + c2) * 64 + lane) * 8);
      Wk8[a][c2] = *(const s16x8*)(g_wpack + 1 * 4096 + ((a * 2 + c2) * 64 + lane) * 8);
      Wv8[a][c2] = *(const s16x8*)(g_wpack + 2 * 4096 + ((a * 2 + c2) * 64 + lane) * 8);
    }
#pragma unroll
    for (int c4 = 0; c4 < 4; ++c4)
      Wf4[a][c4] = *(const s16x4*)(g_wpack + 3 * 4096 + ((a * 4 + c4) * 64 + lane) * 4);
  }

  // per-lane source offsets (within a block)
  // Xq inst i: lane -> channel 16i + (lane>>2), row lane&3, 16B quarter
  const uint32_t vq = (uint32_t)(lane >> 2) * 65536u + (uint32_t)(lane & 3) * 256u;
  // Xr inst m=kt*8+j: lane -> channel 32kt+8g+j, pixel (rp,wl)
  const uint32_t vr = (uint32_t)g * 524288u + (uint32_t)rp * 256u + (uint32_t)wl;

  float* xrb = &sXr[wv][0];
  float* qA  = &sQ[0][wv][0];
  float* qB  = &sQ[1][wv][0];
  u16*   sPw = &sP[wv * 320];

  // XCD-contiguous swizzle over 1024 = 8 * 128 WGs; 8 strips per WG
  const int bid = blockIdx.x;
  const int wid = (bid & 7) * 128 + (bid >> 3);
  const int si0 = wid * 8;

  auto sbase = [](int si) -> uint32_t {
    return ((uint32_t)si >> 10) * 4194304u + (((uint32_t)si >> 4) & 63) * 1024u +
           ((uint32_t)si & 15) * 16u;
  };
  const uint32_t wv4 = (uint32_t)wv * 4u;   // block column within strip

  // ---- prologue: strip-0 Xr + Xq loads for this wave's block, full drain ----
  uint32_t sb = sbase(si0);
#pragma unroll
  for (int m = 0; m < 16; ++m)
    gload_lds4(rx + sb + wv4 + vr + (uint32_t)((m >> 3) * 32 + (m & 7)) * 65536u,
               &xrb[m * 64]);
#pragma unroll
  for (int i = 0; i < 4; ++i)
    gload_lds16(qx + sb + wv4 + vq + (uint32_t)i * 1048576u, &qA[i * 264]);
  asm volatile("s_waitcnt vmcnt(0)" ::: "memory");

  const f32x4 zero = {0.f, 0.f, 0.f, 0.f};

#pragma unroll 1
  for (int t = 0; t < 8; ++t) {
    const uint32_t nsb = sbase(si0 + (t < 7 ? t + 1 : t));
    float* qc = (t & 1) ? qB : qA;   // current block (loaded last iter)
    float* qn = (t & 1) ? qA : qB;   // next-block destination

    // gate: Xr(t)+Xq(t) complete (the 4 stores of t-1 stay in flight)
    asm volatile("s_waitcnt vmcnt(4)" ::: "memory");
    __builtin_amdgcn_sched_barrier(0);

    // ---- Xr(t) readback (own LDS, 2-way banks) + split cvt ----
    s16x8 frh[2], frl[2];
#pragma unroll
    for (int kt = 0; kt < 2; ++kt)
#pragma unroll
      for (int j = 0; j < 8; ++j) {
        float x2 = xrb[(kt * 8 + j) * 64 + lane];
        bf16 h = (bf16)x2;
        frh[kt][j] = (short)__builtin_bit_cast(u16, h);
        frl[kt][j] = (short)bfbits(x2 - (float)h);
      }
    __builtin_amdgcn_sched_barrier(0);

    // ---- issue Xr(t+1) (same buffer; reads above already in LDS pipe) ----
    if (t < 7) {
#pragma unroll
      for (int m = 0; m < 16; ++m)
        gload_lds4(rx + nsb + wv4 + vr + (uint32_t)((m >> 3) * 32 + (m & 7)) * 65536u,
                   &xrb[m * 64]);
      // ---- issue Xq(t+1) into the other ping-pong buffer ----
#pragma unroll
      for (int i = 0; i < 4; ++i)
        gload_lds16(qx + nsb + wv4 + vq + (uint32_t)i * 1048576u, &qn[i * 264]);
    }
    __builtin_amdgcn_sched_barrier(0);

    // ---- Xq(t) extract from own LDS + q projection ----
    s16x8 fqh[2], fql[2];
#pragma unroll
    for (int kt = 0; kt < 2; ++kt)
#pragma unroll
      for (int j = 0; j < 8; ++j) {
        const int c = 32 * kt + 8 * g + j;
        float x1 = qc[(c >> 4) * 264 + (c & 15) * 16 + n];
        bf16 h = (bf16)x1;
        fqh[kt][j] = (short)__builtin_bit_cast(u16, h);
        fql[kt][j] = (short)bfbits(x1 - (float)h);
      }
    f32x4 aq[4];
#pragma unroll
    for (int mt = 0; mt < 4; ++mt) {
      aq[mt] = zero;
#pragma unroll
      for (int kt = 0; kt < 2; ++kt) {
        aq[mt] = MFMA32(Wq8[mt][kt], fqh[kt], aq[mt]);
        aq[mt] = MFMA32(Wq8[mt][kt], fql[kt], aq[mt]);
      }
    }

    // ---- k,v projections ----
    f32x4 ak[4], av[4];
#pragma unroll
    for (int mt = 0; mt < 4; ++mt) { ak[mt] = zero; av[mt] = zero; }
#pragma unroll
    for (int mt = 0; mt < 4; ++mt)
#pragma unroll
      for (int kt = 0; kt < 2; ++kt) {
        ak[mt] = MFMA32(Wk8[mt][kt], frh[kt], ak[mt]);
        ak[mt] = MFMA32(Wk8[mt][kt], frl[kt], ak[mt]);
      }
#pragma unroll
    for (int nt2 = 0; nt2 < 4; ++nt2)
#pragma unroll
      for (int kt = 0; kt < 2; ++kt)
        av[nt2] = MFMA32(frh[kt], Wv8[nt2][kt], av[nt2]);

    // ---- split q,k accumulators (energy frags, same lane) ----
    s16x4 qh[4], ql[4], kh[4], kl[4];
#pragma unroll
    for (int kt = 0; kt < 4; ++kt)
#pragma unroll
      for (int r = 0; r < 4; ++r) {
        bf16 h = (bf16)aq[kt][r];
        qh[kt][r] = (short)__builtin_bit_cast(u16, h);
        ql[kt][r] = (short)bfbits(aq[kt][r] - (float)h);
        bf16 h2 = (bf16)ak[kt][r];
        kh[kt][r] = (short)__builtin_bit_cast(u16, h2);
        kl[kt][r] = (short)bfbits(ak[kt][r] - (float)h2);
      }

    // ---- energy = q^T k : 3 independent chains ----
    f32x4 e0 = zero, e1 = zero, e2 = zero;
#pragma unroll
    for (int kt = 0; kt < 4; ++kt) {
      e0 = MFMA16(qh[kt], kh[kt], e0);
      e1 = MFMA16(qh[kt], kl[kt], e1);
      e2 = MFMA16(ql[kt], kh[kt], e2);
    }

    // ---- softmax over refpix (DPP row butterflies) ----
#pragma unroll
    for (int r = 0; r < 4; ++r) {
      float x = (e0[r] + e1[r]) + e2[r];
      float m = x;
      m = fmaxf(m, DPP_ROR(m, 8));
      m = fmaxf(m, DPP_ROR(m, 4));
      m = fmaxf(m, DPP_ROR(m, 2));
      m = fmaxf(m, DPP_ROR(m, 1));
      float p = __expf(x - m);
      float s = p;
      s += DPP_ROR(s, 8);
      s += DPP_ROR(s, 4);
      s += DPP_ROR(s, 2);
      s += DPP_ROR(s, 1);
      sPw[(4 * g + r) * 20 + n] = bfbits(p * __builtin_amdgcn_rcpf(s));
    }

    // ---- O tiles: A = v (same lane), B = attn^T via own sP ----
    s16x4 pa = *(const s16x4*)&sPw[n * 20 + 4 * g];
    f32x4 ao[4];
#pragma unroll
    for (int mt = 0; mt < 4; ++mt) {
      s16x4 vb;
#pragma unroll
      for (int j = 0; j < 4; ++j) vb[j] = (short)bfbits(av[mt][j]);
      ao[mt] = MFMA16(vb, pa, zero);
    }

    // ---- x = Wfc * O (K16) ----
    s16x4 ob[4];
#pragma unroll
    for (int kt = 0; kt < 4; ++kt)
#pragma unroll
      for (int j = 0; j < 4; ++j) ob[kt][j] = (short)bfbits(ao[kt][j]);
    f32x4 xa[4];
#pragma unroll
    for (int mt = 0; mt < 4; ++mt) {
      xa[mt] = zero;
#pragma unroll
      for (int kt = 0; kt < 4; ++kt)
        xa[mt] = MFMA16(Wf4[mt][kt], ob[kt], xa[mt]);
    }

    // ---- GroupNorm over 64x16: DPP rows + 2 shfl ----
    float s1 = 0.f, s2 = 0.f;
#pragma unroll
    for (int mt = 0; mt < 4; ++mt)
#pragma unroll
      for (int r = 0; r < 4; ++r) {
        float v = xa[mt][r];
        s1 += v; s2 += v * v;
      }
    s1 += DPP_ROR(s1, 8);  s2 += DPP_ROR(s2, 8);
    s1 += DPP_ROR(s1, 4);  s2 += DPP_ROR(s2, 4);
    s1 += DPP_ROR(s1, 2);  s2 += DPP_ROR(s2, 2);
    s1 += DPP_ROR(s1, 1);  s2 += DPP_ROR(s2, 1);
    s1 += __shfl_xor(s1, 16);  s2 += __shfl_xor(s2, 16);
    s1 += __shfl_xor(s1, 32);  s2 += __shfl_xor(s2, 32);
    const float mean = s1 * (1.f / 1024.f);
    const float var  = s2 * (1.f / 1024.f) - mean * mean;
    const float rstd = rsqrtf(var + 1e-5f);

    // ---- affine + exact residual: RMW own buffer ----
#pragma unroll
    for (int mt = 0; mt < 4; ++mt)
#pragma unroll
      for (int r = 0; r < 4; ++r) {
        const int row = 16 * mt + 4 * g + r;
        const int addr = mt * 264 + (4 * g + r) * 16 + n;
        qc[addr] = (xa[mt][r] - mean) * rstd * sGn[row] + sGn[64 + row] + qc[addr];
      }

    // ---- store own block (ds_read_b128 + non-temporal store) ----
#pragma unroll
    for (int i = 0; i < 4; ++i) {
      f4 o = *(const f4*)&qc[i * 264 + lane * 4];
      __builtin_nontemporal_store(
          o, (f4*)(out + sb + wv4 + vq + (uint32_t)i * 1048576u));
    }

    sb = nsb;
  }
}

extern "C" void kernel_launch(void* const* d_in, const int* in_sizes, int n_in,
                              void* d_out, int out_size, void* d_ws, size_t ws_size,
                              hipStream_t stream) {
  const float* qx  = (const float*)d_in[0];
  const float* rx  = (const float*)d_in[1];
  const float* Wq  = (const float*)d_in[2];
  const float* Wk  = (const float*)d_in[3];
  const float* Wv  = (const float*)d_in[4];
  const float* Wfc = (const float*)d_in[5];
  const float* gw  = (const float*)d_in[6];
  const float* gb  = (const float*)d_in[7];
  float* out = (float*)d_out;

  prep_w<<<dim3(1), dim3(256), 0, stream>>>(Wq, Wk, Wv, Wfc);
  // 1024 WGs x 4 independent waves x 8 blocks; zero in-loop barriers
  cvbt15<<<dim3(1024), dim3(256), 0, stream>>>(qx, rx, gw, gb, out);
}